// Round 2
// baseline (225.219 us; speedup 1.0000x reference)
//
#include <hip/hip_runtime.h>
#include <stdint.h>

typedef float  f32x4 __attribute__((ext_vector_type(4)));
typedef short  s16x8 __attribute__((ext_vector_type(8)));
typedef unsigned int u32;
typedef u32    u32x2 __attribute__((ext_vector_type(2)));
typedef unsigned short u16;

#define MFMA16(a,b,c) __builtin_amdgcn_mfma_f32_16x16x32_bf16((a),(b),(c),0,0,0)

__device__ __forceinline__ u16 f2bf(float f){
  u32 u = __float_as_uint(f);
  return (u16)((u + 0x7fffu + ((u >> 16) & 1u)) >> 16);   // RNE
}
__device__ __forceinline__ float bf2f(u16 h){ return __uint_as_float(((u32)h) << 16); }
__device__ __forceinline__ u32 pack2bf(float a, float b){ return (u32)f2bf(a) | ((u32)f2bf(b) << 16); }
__device__ __forceinline__ f32x4 f4zero(){ f32x4 z; z[0]=0.f; z[1]=0.f; z[2]=0.f; z[3]=0.f; return z; }

// async global->LDS, 16B per lane; LDS dest is wave-uniform base + lane*16
__device__ __forceinline__ void async16(const void* g, void* l){
  __builtin_amdgcn_global_load_lds(
      (const __attribute__((address_space(1))) unsigned int*)g,
      (__attribute__((address_space(3))) unsigned int*)l, 16, 0, 0);
}

// ---------------------------------------------------------------------------
// K1: split x -> xh/xl (bf16 hi/lo), build Xt (bf16 x transposed per batch),
//     and (block 0/1) prep wr^T hi/lo and w1^T bf16.
// ---------------------------------------------------------------------------
__global__ __launch_bounds__(256) void k_prep(
    const float* __restrict__ x, const float* __restrict__ wr, const float* __restrict__ w1,
    u16* __restrict__ xh, u16* __restrict__ xl, u16* __restrict__ Xt,
    u16* __restrict__ wrth, u16* __restrict__ wrtl, u16* __restrict__ w1t)
{
  __shared__ float xs[16][132];
  const int tid = threadIdx.x, bid = blockIdx.x;
  const long base = (long)bid * 2048;          // 16 rows * 128
#pragma unroll
  for (int k = 0; k < 8; k++){
    int idx = tid + k*256;
    float v = x[base + idx];
    xs[idx>>7][idx&127] = v;
    u16 h = f2bf(v);
    xh[base+idx] = h;
    xl[base+idx] = f2bf(v - bf2f(h));
  }
  __syncthreads();
  const int b  = bid >> 7;                     // 128 blocks per batch
  const int n0 = (bid & 127) * 16;
  const int nn = tid & 15, d0 = tid >> 4;
#pragma unroll
  for (int d = 0; d < 8; d++){
    int dd = d0 + d*16;
    Xt[(long)b*262144 + (long)dd*2048 + n0 + nn] = f2bf(xs[nn][dd]);
  }
  if (bid == 0){
#pragma unroll
    for (int k = 0; k < 64; k++){
      int idx = tid + k*256;
      int g = idx >> 7, f = idx & 127;
      float v = wr[f*128 + g];                 // wrT[g][f] = wr[f][g]
      u16 h = f2bf(v);
      wrth[idx] = h;
      wrtl[idx] = f2bf(v - bf2f(h));
    }
  } else if (bid == 1){
#pragma unroll
    for (int k = 0; k < 64; k++){
      int idx = tid + k*256;
      int c = idx >> 7, f = idx & 127;
      w1t[idx] = f2bf(w1[f*128 + c]);          // w1T[c][f] = w1[f][c]
    }
  }
}

// ---------------------------------------------------------------------------
// K2: y = (x @ wr) * log2(e)  via 3-term split bf16 MFMA; write yh/yl hi/lo
//     (log2e prescale makes all flash exps native exp2)
// ---------------------------------------------------------------------------
__global__ __launch_bounds__(128, 2) void k_ygemm(
    const u16* __restrict__ xh, const u16* __restrict__ xl,
    const u16* __restrict__ wrth, const u16* __restrict__ wrtl,
    u16* __restrict__ yh, u16* __restrict__ yl)
{
  __shared__ u16 sbh[16384], sbl[16384];       // [c][f] bf16, XOR-swizzled
  const int tid = threadIdx.x, bid = blockIdx.x;
#pragma unroll
  for (int k = 0; k < 16; k++){
    int off = (tid + k*128) * 16;
    int row = off >> 8;
    int dst = off ^ ((row & 7) << 4);
    *(s16x8*)((char*)sbh + dst) = *(const s16x8*)((const char*)wrth + off);
    *(s16x8*)((char*)sbl + dst) = *(const s16x8*)((const char*)wrtl + off);
  }
  __syncthreads();
  const int w = tid >> 6, lane = tid & 63, lr = lane & 15, g = lane >> 4;
  const long rowbase = (long)bid*64 + w*32;
  s16x8 ah[2][4], al[2][4];
#pragma unroll
  for (int rh = 0; rh < 2; rh++)
#pragma unroll
    for (int kc = 0; kc < 4; kc++){
      long r = rowbase + rh*16 + lr;
      ah[rh][kc] = *(const s16x8*)(xh + r*128 + kc*32 + g*8);
      al[rh][kc] = *(const s16x8*)(xl + r*128 + kc*32 + g*8);
    }
  f32x4 acc[2][8];
#pragma unroll
  for (int rh = 0; rh < 2; rh++)
#pragma unroll
    for (int cg = 0; cg < 8; cg++) acc[rh][cg] = f4zero();
  const int swz = (lr & 7) << 4;
#pragma unroll
  for (int cg = 0; cg < 8; cg++){
    const int rowt = (cg*16 + lr) * 256;
#pragma unroll
    for (int kc = 0; kc < 4; kc++){
      int boff = rowt + ((kc*64 + g*16) ^ swz);
      s16x8 bh = *(const s16x8*)((const char*)sbh + boff);
      s16x8 bl = *(const s16x8*)((const char*)sbl + boff);
#pragma unroll
      for (int rh = 0; rh < 2; rh++){
        acc[rh][cg] = MFMA16(ah[rh][kc], bh, acc[rh][cg]);
        acc[rh][cg] = MFMA16(al[rh][kc], bh, acc[rh][cg]);
        acc[rh][cg] = MFMA16(ah[rh][kc], bl, acc[rh][cg]);
      }
    }
  }
#pragma unroll
  for (int rh = 0; rh < 2; rh++)
#pragma unroll
    for (int cg = 0; cg < 8; cg++)
#pragma unroll
      for (int r = 0; r < 4; r++){
        long q = rowbase + rh*16 + 4*g + r;    // C-layout: row=(l>>4)*4+reg
        int  c = cg*16 + lr;                   //           col=l&15
        float v = acc[rh][cg][r] * 1.4426950408889634f;
        u16 h = f2bf(v);
        yh[q*128 + c] = h;
        yl[q*128 + c] = f2bf(v - bf2f(h));
      }
}

// ---------------------------------------------------------------------------
// K3: fused flash, swapped-operand form.
//   S^T tile = X_tile (LDS, A-op) x Y^T (regs, B-op)  -> lane-local softmax
//   O^T     += Xt (global L2, A-op) x P^T (LDS bounce, B-op)
//   grid = 128 qb * KS; XCD swizzle: batch = bid & 7
// ---------------------------------------------------------------------------
__global__ __launch_bounds__(256, 3) void k_flash(
    const u16* __restrict__ xh, const u16* __restrict__ xl, const u16* __restrict__ Xt,
    const u16* __restrict__ yh, const u16* __restrict__ yl,
    u16* __restrict__ A1bf,
    u16* __restrict__ Opart, float* __restrict__ mpart, float* __restrict__ lpart,
    int KS, int kslog)
{
  __shared__ u16 sxh[2][4096], sxl[2][4096];   // 32kv x 128f tiles, XOR-swizzled
  __shared__ u16 sP[4][1280];                  // per-warp P [32 q][40] (pad 40)
  const int tid = threadIdx.x, bid = blockIdx.x;
  const int b     = bid & 7;                   // XCD b owns batch b
  const int inner = bid >> 3;
  const int s     = inner & (KS - 1);
  const int qbl   = inner >> kslog;
  const int qb    = b*16 + qbl;
  const int nspan = 2048 >> kslog;
  const int kv0   = s * nspan;
  const int ntiles = nspan >> 5;
  const int w = tid >> 6, lane = tid & 63, lr = lane & 15, g = lane >> 4;
  const long qrow = (long)qb*128 + w*32;

  // Y fragments (B-operands), hi/lo — per-warp constants
  s16x8 byh[2][4], byl[2][4];
#pragma unroll
  for (int qh = 0; qh < 2; qh++)
#pragma unroll
    for (int kc = 0; kc < 4; kc++){
      long r = qrow + qh*16 + lr;
      byh[qh][kc] = *(const s16x8*)(yh + r*128 + kc*32 + g*8);
      byl[qh][kc] = *(const s16x8*)(yl + r*128 + kc*32 + g*8);
    }

  f32x4 o[8][2];                               // O^T: [d-tile dg][q-half qh]
#pragma unroll
  for (int dg = 0; dg < 8; dg++){ o[dg][0] = f4zero(); o[dg][1] = f4zero(); }
  float mrun[2] = {-1e30f, -1e30f}, lrun[2] = {0.f, 0.f};

  const char* gxh = (const char*)xh + ((long)b*2048 + kv0)*256;
  const char* gxl = (const char*)xl + ((long)b*2048 + kv0)*256;
  const u16*  gxt = Xt + (long)b*262144 + kv0;

  auto stage = [&](int bufi, int t){
#pragma unroll
    for (int c2 = 0; c2 < 2; c2++){
      int chunk = w*2 + c2;
      int off = chunk*1024 + lane*16;
      int row = off >> 8;
      int swo = off ^ ((row & 7) << 4);        // pre-swizzled global source
      async16(gxh + (long)t*8192 + swo, &sxh[bufi][chunk*512]);
      async16(gxl + (long)t*8192 + swo, &sxl[bufi][chunk*512]);
    }
  };

  stage(0, 0);
  __syncthreads();

  for (int t = 0; t < ntiles; t++){
    const int cur = t & 1;
    if (t + 1 < ntiles) stage(cur ^ 1, t + 1);
    const char* pxh = (const char*)&sxh[cur][0];
    const char* pxl = (const char*)&sxl[cur][0];

    // ---- S^T tile [32kv x 32q], 3-term hi/lo split ----
    f32x4 sacc[2][2];                          // [kv-half ch][q-half qh]
    sacc[0][0] = f4zero(); sacc[0][1] = f4zero();
    sacc[1][0] = f4zero(); sacc[1][1] = f4zero();
    __builtin_amdgcn_s_setprio(1);
#pragma unroll
    for (int ch = 0; ch < 2; ch++){
      const int rowb = ch*16 + lr;
#pragma unroll
      for (int kc = 0; kc < 4; kc++){
        const int boff = rowb*256 + ((kc*64 + g*16) ^ ((rowb & 7) << 4));
        s16x8 fh = *(const s16x8*)(pxh + boff);
        s16x8 fl = *(const s16x8*)(pxl + boff);
#pragma unroll
        for (int qh = 0; qh < 2; qh++){
          sacc[ch][qh] = MFMA16(fh, byh[qh][kc], sacc[ch][qh]);
          sacc[ch][qh] = MFMA16(fl, byh[qh][kc], sacc[ch][qh]);
          sacc[ch][qh] = MFMA16(fh, byl[qh][kc], sacc[ch][qh]);
        }
      }
    }
    __builtin_amdgcn_s_setprio(0);

    // ---- lane-local online softmax (q = qh*16 + lr lives in this lane) ----
#pragma unroll
    for (int qh = 0; qh < 2; qh++){
      float cm = fmaxf(fmaxf(fmaxf(sacc[0][qh][0], sacc[0][qh][1]),
                             fmaxf(sacc[0][qh][2], sacc[0][qh][3])),
                       fmaxf(fmaxf(sacc[1][qh][0], sacc[1][qh][1]),
                             fmaxf(sacc[1][qh][2], sacc[1][qh][3])));
      cm = fmaxf(cm, __shfl_xor(cm, 16, 64));
      cm = fmaxf(cm, __shfl_xor(cm, 32, 64));
      if (__any(cm > mrun[qh] + 8.f)){         // defer-max (log2 units, P<=256)
        float mn = fmaxf(mrun[qh], cm);
        float sc = exp2f(mrun[qh] - mn);
#pragma unroll
        for (int dg = 0; dg < 8; dg++)
#pragma unroll
          for (int r = 0; r < 4; r++) o[dg][qh][r] *= sc;
        lrun[qh] *= sc;
        mrun[qh] = mn;
      }
      float p[2][4];
#pragma unroll
      for (int ch = 0; ch < 2; ch++)
#pragma unroll
        for (int r = 0; r < 4; r++) p[ch][r] = exp2f(sacc[ch][qh][r] - mrun[qh]);
      float ls = ((p[0][0] + p[0][1]) + (p[0][2] + p[0][3]))
               + ((p[1][0] + p[1][1]) + (p[1][2] + p[1][3]));
      ls += __shfl_xor(ls, 16, 64);
      ls += __shfl_xor(ls, 32, 64);
      lrun[qh] += ls;
      // P^T -> sP[q][kv] (layout [32][40]); lane writes kv = 16ch+4g+0..3
#pragma unroll
      for (int ch = 0; ch < 2; ch++){
        u32x2 pw;
        pw[0] = pack2bf(p[ch][0], p[ch][1]);
        pw[1] = pack2bf(p[ch][2], p[ch][3]);
        *(u32x2*)&sP[w][(qh*16 + lr)*40 + ch*16 + 4*g] = pw;
      }
    }

    // ---- O^T += Xt^T-frag x P^T  (A from global L2, B from sP) ----
    s16x8 ax[8];
#pragma unroll
    for (int dg = 0; dg < 8; dg++)
      ax[dg] = *(const s16x8*)(gxt + (long)(dg*16 + lr)*2048 + t*32 + g*8);
    s16x8 bp[2];
    bp[0] = *(const s16x8*)(&sP[w][(lr)*40 + g*8]);
    bp[1] = *(const s16x8*)(&sP[w][(16 + lr)*40 + g*8]);
    __builtin_amdgcn_s_setprio(1);
#pragma unroll
    for (int dg = 0; dg < 8; dg++){
      o[dg][0] = MFMA16(ax[dg], bp[0], o[dg][0]);
      o[dg][1] = MFMA16(ax[dg], bp[1], o[dg][1]);
    }
    __builtin_amdgcn_s_setprio(0);
    __syncthreads();   // drains prefetch + guards buffer reuse
  }

  // ---- epilogue: O^T lane holds (d = dg*16+4g+r, q = qh*16+lr) ----
  if (KS == 1){
#pragma unroll
    for (int qh = 0; qh < 2; qh++){
      float inv = 1.f / lrun[qh];
      long q = qrow + qh*16 + lr;
#pragma unroll
      for (int dg = 0; dg < 8; dg++){
        u32x2 pw;
        pw[0] = pack2bf(o[dg][qh][0]*inv, o[dg][qh][1]*inv);
        pw[1] = pack2bf(o[dg][qh][2]*inv, o[dg][qh][3]*inv);
        *(u32x2*)(A1bf + q*128 + dg*16 + 4*g) = pw;
      }
    }
  } else {
    const long pid = bid;
#pragma unroll
    for (int qh = 0; qh < 2; qh++){
      int lq = w*32 + qh*16 + lr;
#pragma unroll
      for (int dg = 0; dg < 8; dg++){
        u32x2 pw;
        pw[0] = pack2bf(o[dg][qh][0], o[dg][qh][1]);
        pw[1] = pack2bf(o[dg][qh][2], o[dg][qh][3]);
        *(u32x2*)(Opart + pid*16384 + (long)lq*128 + dg*16 + 4*g) = pw;
      }
      if (g == 0){
        mpart[pid*128 + lq] = mrun[qh];
        lpart[pid*128 + lq] = lrun[qh];
      }
    }
  }
}

// ---------------------------------------------------------------------------
// K4: merge kv-split partials -> normalized A1 (bf16). m's are log2-units.
// ---------------------------------------------------------------------------
__global__ __launch_bounds__(256) void k_merge(
    const u16* __restrict__ Opart, const float* __restrict__ mpart, const float* __restrict__ lpart,
    u16* __restrict__ A1bf, int KS)
{
  const int tid = threadIdx.x, bid = blockIdx.x;
  const long R = (long)bid*2 + (tid >> 7);
  const int d = tid & 127;
  const int qb = (int)(R >> 7), r = (int)(R & 127);
  const int pbase = (qb >> 4);                 // batch bits (bid & 7)
  const int qblk  = (qb & 15);
  float m = -1e30f;
  for (int s = 0; s < KS; s++){
    long pid = (long)((qblk*KS + s)*8 + pbase);
    m = fmaxf(m, mpart[pid*128 + r]);
  }
  float acc = 0.f, ls = 0.f;
  for (int s = 0; s < KS; s++){
    long pid = (long)((qblk*KS + s)*8 + pbase);
    float wgt = exp2f(mpart[pid*128 + r] - m);
    ls  += lpart[pid*128 + r] * wgt;
    acc += bf2f(Opart[pid*16384 + (long)r*128 + d]) * wgt;
  }
  A1bf[R*128 + d] = f2bf(acc / ls);
}

// ---------------------------------------------------------------------------
// K5: x1 = relu(A1 @ w1 + x)  (bf16 MFMA, fp32 out)
// ---------------------------------------------------------------------------
__global__ __launch_bounds__(128, 2) void k_layer1(
    const u16* __restrict__ A1bf, const u16* __restrict__ w1t,
    const float* __restrict__ x, float* __restrict__ x1)
{
  __shared__ u16 sb[16384];
  const int tid = threadIdx.x, bid = blockIdx.x;
#pragma unroll
  for (int k = 0; k < 16; k++){
    int off = (tid + k*128)*16;
    int row = off >> 8;
    *(s16x8*)((char*)sb + (off ^ ((row & 7) << 4))) = *(const s16x8*)((const char*)w1t + off);
  }
  __syncthreads();
  const int w = tid >> 6, lane = tid & 63, lr = lane & 15, g = lane >> 4;
  const long rowbase = (long)bid*64 + w*32;
  s16x8 aa[2][4];
#pragma unroll
  for (int rh = 0; rh < 2; rh++)
#pragma unroll
    for (int kc = 0; kc < 4; kc++)
      aa[rh][kc] = *(const s16x8*)(A1bf + (rowbase + rh*16 + lr)*128 + kc*32 + g*8);
  f32x4 acc[2][8];
#pragma unroll
  for (int rh = 0; rh < 2; rh++)
#pragma unroll
    for (int cg = 0; cg < 8; cg++) acc[rh][cg] = f4zero();
  const int swz = (lr & 7) << 4;
#pragma unroll
  for (int cg = 0; cg < 8; cg++){
    const int rowt = (cg*16 + lr)*256;
#pragma unroll
    for (int kc = 0; kc < 4; kc++){
      s16x8 bb = *(const s16x8*)((const char*)sb + rowt + ((kc*64 + g*16) ^ swz));
#pragma unroll
      for (int rh = 0; rh < 2; rh++)
        acc[rh][cg] = MFMA16(aa[rh][kc], bb, acc[rh][cg]);
    }
  }
#pragma unroll
  for (int rh = 0; rh < 2; rh++)
#pragma unroll
    for (int cg = 0; cg < 8; cg++)
#pragma unroll
      for (int r = 0; r < 4; r++){
        long q = rowbase + rh*16 + 4*g + r;
        int  c = cg*16 + lr;
        float v = acc[rh][cg][r] + x[q*128 + c];
        x1[q*128 + c] = fmaxf(v, 0.f);
      }
}

// ---------------------------------------------------------------------------
// K6: exact fp32 row-0 logits  S0[b,m] = (x[b,0,:] @ wr) . x[b,m,:]
// ---------------------------------------------------------------------------
__global__ __launch_bounds__(256) void k_s0(
    const float* __restrict__ x, const float* __restrict__ wr,
    float* __restrict__ S0, float* __restrict__ maxpart)
{
  __shared__ float x0s[128];
  __shared__ float ys[128];
  __shared__ float red[256];
  const int tid = threadIdx.x, bid = blockIdx.x;
  const int b = bid >> 3, j = bid & 7;
  if (tid < 128) x0s[tid] = x[(long)b*262144 + tid];
  __syncthreads();
  if (tid < 128){
    float a = 0.f;
    for (int f = 0; f < 128; f++) a += x0s[f] * wr[f*128 + tid];
    ys[tid] = a;
  }
  __syncthreads();
  const int m = j*256 + tid;
  const float4* xr = (const float4*)(x + ((long)b*2048 + m)*128);
  const float4* yv = (const float4*)ys;
  float acc = 0.f;
#pragma unroll
  for (int f = 0; f < 32; f++){
    float4 a = xr[f], c = yv[f];
    acc += a.x*c.x + a.y*c.y + a.z*c.z + a.w*c.w;
  }
  S0[b*2048 + m] = acc;
  red[tid] = acc;
  __syncthreads();
  for (int sft = 128; sft > 0; sft >>= 1){
    if (tid < sft) red[tid] = fmaxf(red[tid], red[tid + sft]);
    __syncthreads();
  }
  if (tid == 0) maxpart[bid] = red[0];
}

// K7: row-0 softmax (fp32 exact)
__global__ __launch_bounds__(256) void k_r0(
    const float* __restrict__ S0, const float* __restrict__ maxpart, float* __restrict__ R0)
{
  __shared__ float red[256];
  const int tid = threadIdx.x, b = blockIdx.x;
  float M = -1e30f;
#pragma unroll
  for (int jj = 0; jj < 8; jj++) M = fmaxf(M, maxpart[b*8 + jj]);
  float sv[8]; float se = 0.f;
#pragma unroll
  for (int k = 0; k < 8; k++){
    sv[k] = __expf(S0[b*2048 + tid + k*256] - M);
    se += sv[k];
  }
  red[tid] = se;
  __syncthreads();
  for (int sft = 128; sft > 0; sft >>= 1){
    if (tid < sft) red[tid] += red[tid + sft];
    __syncthreads();
  }
  float inv = 1.f / red[0];
#pragma unroll
  for (int k = 0; k < 8; k++) R0[b*2048 + tid + k*256] = sv[k]*inv;
}

// K8: A2 partials  A2p[b,j,:] = sum_{m in chunk j} R0[b,m] * x1[b,m,:]
__global__ __launch_bounds__(256) void k_a2(
    const float* __restrict__ R0, const float* __restrict__ x1, float* __restrict__ A2p)
{
  __shared__ float red[128];
  const int tid = threadIdx.x, bid = blockIdx.x;
  const int b = bid >> 3, j = bid & 7;
  const int d = tid & 127, h = tid >> 7;
  float acc = 0.f;
  for (int mi = j*256 + h; mi < j*256 + 256; mi += 2)
    acc += R0[b*2048 + mi] * x1[((long)b*2048 + mi)*128 + d];
  if (h == 1) red[d] = acc;
  __syncthreads();
  if (h == 0) A2p[(long)bid*128 + d] = acc + red[d];
}

// K9: out = relu(A2 @ w2 + x1[:,0,:])
__global__ __launch_bounds__(256) void k_out(
    const float* __restrict__ A2p, const float* __restrict__ w2,
    const float* __restrict__ x1, float* __restrict__ out)
{
  __shared__ float a2s[2][128];
  const int tid = threadIdx.x, bid = blockIdx.x;
  const int b0 = bid*2;
  {
    int which = tid >> 7, f = tid & 127;
    float s = 0.f;
#pragma unroll
    for (int jj = 0; jj < 8; jj++) s += A2p[(long)((b0 + which)*8 + jj)*128 + f];
    a2s[which][f] = s;
  }
  __syncthreads();
  const int which = tid >> 7, d = tid & 127;
  const int b = b0 + which;
  float acc = x1[(long)b*262144 + d];
  for (int f = 0; f < 128; f++)
    acc += a2s[which][f] * w2[f*128 + d];
  out[b*128 + d] = fmaxf(acc, 0.f);
}

// ---------------------------------------------------------------------------
extern "C" void kernel_launch(void* const* d_in, const int* in_sizes, int n_in,
                              void* d_out, int out_size, void* d_ws, size_t ws_size,
                              hipStream_t stream)
{
  const float* x  = (const float*)d_in[0];
  const float* w1 = (const float*)d_in[1];
  const float* w2 = (const float*)d_in[2];
  const float* wr = (const float*)d_in[3];
  float* out = (float*)d_out;
  char* ws = (char*)d_ws;

  u16*   xh      = (u16*)  (ws + 0);
  u16*   xl      = (u16*)  (ws + 4194304);
  u16*   Xt      = (u16*)  (ws + 8388608);
  u16*   yh      = (u16*)  (ws + 12582912);
  u16*   yl      = (u16*)  (ws + 16777216);
  u16*   wrth    = (u16*)  (ws + 20971520);
  u16*   wrtl    = (u16*)  (ws + 21004288);
  u16*   w1t     = (u16*)  (ws + 21037056);
  u16*   A1bf    = (u16*)  (ws + 21069824);
  float* R0      = (float*)(ws + 25264128);
  float* S0      = (float*)(ws + 25329664);
  float* maxpart = (float*)(ws + 25395200);
  float* A2p     = (float*)(ws + 25396224);
  // flash partials live in [25428992, ...) and are DEAD before x1 is written,
  // so x1 aliases the same region (written by k_layer1 after k_merge).
  const size_t tail = 25428992;

  int KS = 8, kslog = 3;
  while (KS > 1 && tail + (size_t)KS*(131072 + 4194304) > ws_size){ KS >>= 1; kslog--; }
  float* mpart = (float*)(ws + tail);
  float* lpart = (float*)(ws + tail + (size_t)KS*65536);
  u16*   Opart = (u16*)  (ws + tail + (size_t)KS*131072);
  float* x1    = (float*)(ws + tail);          // aliases mpart/lpart/Opart (dead)

  k_prep  <<<1024, 256, 0, stream>>>(x, wr, w1, xh, xl, Xt, wrth, wrtl, w1t);
  k_ygemm <<<256, 128, 0, stream>>>(xh, xl, wrth, wrtl, yh, yl);
  k_flash <<<128*KS, 256, 0, stream>>>(xh, xl, Xt, yh, yl, A1bf, Opart, mpart, lpart, KS, kslog);
  if (KS > 1)
    k_merge <<<8192, 256, 0, stream>>>(Opart, mpart, lpart, A1bf, KS);
  k_layer1<<<256, 128, 0, stream>>>(A1bf, w1t, x, x1);
  k_s0    <<<64, 256, 0, stream>>>(x, wr, S0, maxpart);
  k_r0    <<<8, 256, 0, stream>>>(S0, maxpart, R0);
  k_a2    <<<64, 256, 0, stream>>>(R0, x1, A2p);
  k_out   <<<4, 256, 0, stream>>>(A2p, w2, x1, out);
}

// Round 4
// 179.721 us; speedup vs baseline: 1.2532x; 1.2532x over previous
//
#include <hip/hip_runtime.h>
#include <stdint.h>

typedef float  f32x4 __attribute__((ext_vector_type(4)));
typedef short  s16x8 __attribute__((ext_vector_type(8)));
typedef unsigned int u32;
typedef u32    u32x2 __attribute__((ext_vector_type(2)));
typedef unsigned short u16;

#define MFMA16(a,b,c) __builtin_amdgcn_mfma_f32_16x16x32_bf16((a),(b),(c),0,0,0)

__device__ __forceinline__ u16 f2bf(float f){
  u32 u = __float_as_uint(f);
  return (u16)((u + 0x7fffu + ((u >> 16) & 1u)) >> 16);   // RNE
}
__device__ __forceinline__ float bf2f(u16 h){ return __uint_as_float(((u32)h) << 16); }
__device__ __forceinline__ u32 pack2bf(float a, float b){ return (u32)f2bf(a) | ((u32)f2bf(b) << 16); }
__device__ __forceinline__ f32x4 f4zero(){ f32x4 z; z[0]=0.f; z[1]=0.f; z[2]=0.f; z[3]=0.f; return z; }
__device__ __forceinline__ s16x8 mk8(u32 a, u32 b, u32 c, u32 d){
  union { u32 w[4]; s16x8 v; } u; u.w[0]=a; u.w[1]=b; u.w[2]=c; u.w[3]=d; return u.v;
}

// async global->LDS, 16B per lane; LDS dest is wave-uniform base + lane*16
__device__ __forceinline__ void async16(const void* g, void* l){
  __builtin_amdgcn_global_load_lds(
      (const __attribute__((address_space(1))) unsigned int*)g,
      (__attribute__((address_space(3))) unsigned int*)l, 16, 0, 0);
}

// ---------------------------------------------------------------------------
// K1: split x -> xh/xl (bf16 hi/lo), build Xt (bf16 x transposed per batch),
//     and (block 0/1) prep wr^T hi/lo and w1^T bf16.
// ---------------------------------------------------------------------------
__global__ __launch_bounds__(256) void k_prep(
    const float* __restrict__ x, const float* __restrict__ wr, const float* __restrict__ w1,
    u16* __restrict__ xh, u16* __restrict__ xl, u16* __restrict__ Xt,
    u16* __restrict__ wrth, u16* __restrict__ wrtl, u16* __restrict__ w1t)
{
  __shared__ float xs[16][132];
  const int tid = threadIdx.x, bid = blockIdx.x;
  const long base = (long)bid * 2048;          // 16 rows * 128
#pragma unroll
  for (int k = 0; k < 8; k++){
    int idx = tid + k*256;
    float v = x[base + idx];
    xs[idx>>7][idx&127] = v;
    u16 h = f2bf(v);
    xh[base+idx] = h;
    xl[base+idx] = f2bf(v - bf2f(h));
  }
  __syncthreads();
  const int b  = bid >> 7;                     // 128 blocks per batch
  const int n0 = (bid & 127) * 16;
  const int nn = tid & 15, d0 = tid >> 4;
#pragma unroll
  for (int d = 0; d < 8; d++){
    int dd = d0 + d*16;
    Xt[(long)b*262144 + (long)dd*2048 + n0 + nn] = f2bf(xs[nn][dd]);
  }
  if (bid == 0){
#pragma unroll
    for (int k = 0; k < 64; k++){
      int idx = tid + k*256;
      int g = idx >> 7, f = idx & 127;
      float v = wr[f*128 + g];                 // wrT[g][f] = wr[f][g]
      u16 h = f2bf(v);
      wrth[idx] = h;
      wrtl[idx] = f2bf(v - bf2f(h));
    }
  } else if (bid == 1){
#pragma unroll
    for (int k = 0; k < 64; k++){
      int idx = tid + k*256;
      int c = idx >> 7, f = idx & 127;
      w1t[idx] = f2bf(w1[f*128 + c]);          // w1T[c][f] = w1[f][c]
    }
  }
}

// ---------------------------------------------------------------------------
// K2: y = (x @ wr) * log2(e)  via 3-term split bf16 MFMA; write yh/yl hi/lo
// ---------------------------------------------------------------------------
__global__ __launch_bounds__(128, 2) void k_ygemm(
    const u16* __restrict__ xh, const u16* __restrict__ xl,
    const u16* __restrict__ wrth, const u16* __restrict__ wrtl,
    u16* __restrict__ yh, u16* __restrict__ yl)
{
  __shared__ u16 sbh[16384], sbl[16384];       // [c][f] bf16, XOR-swizzled
  const int tid = threadIdx.x, bid = blockIdx.x;
#pragma unroll
  for (int k = 0; k < 16; k++){
    int off = (tid + k*128) * 16;
    int row = off >> 8;
    int dst = off ^ ((row & 7) << 4);
    *(s16x8*)((char*)sbh + dst) = *(const s16x8*)((const char*)wrth + off);
    *(s16x8*)((char*)sbl + dst) = *(const s16x8*)((const char*)wrtl + off);
  }
  __syncthreads();
  const int w = tid >> 6, lane = tid & 63, lr = lane & 15, g = lane >> 4;
  const long rowbase = (long)bid*64 + w*32;
  s16x8 ah[2][4], al[2][4];
#pragma unroll
  for (int rh = 0; rh < 2; rh++)
#pragma unroll
    for (int kc = 0; kc < 4; kc++){
      long r = rowbase + rh*16 + lr;
      ah[rh][kc] = *(const s16x8*)(xh + r*128 + kc*32 + g*8);
      al[rh][kc] = *(const s16x8*)(xl + r*128 + kc*32 + g*8);
    }
  f32x4 acc[2][8];
#pragma unroll
  for (int rh = 0; rh < 2; rh++)
#pragma unroll
    for (int cg = 0; cg < 8; cg++) acc[rh][cg] = f4zero();
  const int swz = (lr & 7) << 4;
#pragma unroll
  for (int cg = 0; cg < 8; cg++){
    const int rowt = (cg*16 + lr) * 256;
#pragma unroll
    for (int kc = 0; kc < 4; kc++){
      int boff = rowt + ((kc*64 + g*16) ^ swz);
      s16x8 bh = *(const s16x8*)((const char*)sbh + boff);
      s16x8 bl = *(const s16x8*)((const char*)sbl + boff);
#pragma unroll
      for (int rh = 0; rh < 2; rh++){
        acc[rh][cg] = MFMA16(ah[rh][kc], bh, acc[rh][cg]);
        acc[rh][cg] = MFMA16(al[rh][kc], bh, acc[rh][cg]);
        acc[rh][cg] = MFMA16(ah[rh][kc], bl, acc[rh][cg]);
      }
    }
  }
#pragma unroll
  for (int rh = 0; rh < 2; rh++)
#pragma unroll
    for (int cg = 0; cg < 8; cg++)
#pragma unroll
      for (int r = 0; r < 4; r++){
        long q = rowbase + rh*16 + 4*g + r;    // C-layout: row=(l>>4)*4+reg
        int  c = cg*16 + lr;                   //           col=l&15
        float v = acc[rh][cg][r] * 1.4426950408889634f;
        u16 h = f2bf(v);
        yh[q*128 + c] = h;
        yl[q*128 + c] = f2bf(v - bf2f(h));
      }
}

// ---------------------------------------------------------------------------
// K3: fused flash, swapped-operand form, all tiles LDS-staged + swizzled.
//   S^T tile = X_tile (LDS, A-op) x Y^T (regs, B-op)  -> lane-local softmax
//   P redistributed in-register via 8 shfl + selects (no LDS bounce)
//   O^T     += Xt_tile (LDS, A-op) x P^T (regs, B-op)
//   NOTE sxt rows are 64B = 4x16B granules -> swizzle mask is (row&3)<<4.
//   ((row&7)<<4 crosses the row boundary: non-bijective, was round-3 bug.)
//   grid = 8 batches (XCD-pinned) * 16 qbl * KS
// ---------------------------------------------------------------------------
__global__ __launch_bounds__(256, 3) void k_flash(
    const u16* __restrict__ xh, const u16* __restrict__ xl, const u16* __restrict__ Xt,
    const u16* __restrict__ yh, const u16* __restrict__ yl,
    u16* __restrict__ A1bf,
    float* __restrict__ Opart, float* __restrict__ mpart, float* __restrict__ lpart,
    int KS, int kslog)
{
  __shared__ u16 sxh[2][4096], sxl[2][4096];   // 32kv x 128f, XOR-swz (row&7)
  __shared__ u16 sxt[2][4096];                 // 128d x 32kv, XOR-swz (row&3)
  const int tid = threadIdx.x, bid = blockIdx.x;
  const int b     = bid & 7;                   // XCD b owns batch b
  const int inner = bid >> 3;
  const int s     = inner & (KS - 1);
  const int qbl   = inner >> kslog;
  const int qb    = b*16 + qbl;
  const int nspan = 2048 >> kslog;
  const int kv0   = s * nspan;
  const int ntiles = nspan >> 5;
  const int w = tid >> 6, lane = tid & 63, lr = lane & 15, g = lane >> 4;
  const long qrow = (long)qb*128 + w*32;

  // Y fragments (B-operands), hi/lo — per-warp constants
  s16x8 byh[2][4], byl[2][4];
#pragma unroll
  for (int qh = 0; qh < 2; qh++)
#pragma unroll
    for (int kc = 0; kc < 4; kc++){
      long r = qrow + qh*16 + lr;
      byh[qh][kc] = *(const s16x8*)(yh + r*128 + kc*32 + g*8);
      byl[qh][kc] = *(const s16x8*)(yl + r*128 + kc*32 + g*8);
    }

  f32x4 o[8][2];                               // O^T: [d-tile dg][q-half qh]
#pragma unroll
  for (int dg = 0; dg < 8; dg++){ o[dg][0] = f4zero(); o[dg][1] = f4zero(); }
  float mrun[2] = {-1e30f, -1e30f}, lrun[2] = {0.f, 0.f};

  const char* gxh  = (const char*)xh + ((long)b*2048 + kv0)*256;
  const char* gxl  = (const char*)xl + ((long)b*2048 + kv0)*256;
  const char* gxtb = (const char*)(Xt + (long)b*262144 + kv0);

  auto stage = [&](int bufi, int t){
#pragma unroll
    for (int c2 = 0; c2 < 2; c2++){
      int chunk = w*2 + c2;
      int off = chunk*1024 + lane*16;
      {  // x tiles: rows of 256B (16 granules), swizzle by row&7
        int row = off >> 8;
        int swo = off ^ ((row & 7) << 4);
        async16(gxh + (long)t*8192 + swo, &sxh[bufi][chunk*512]);
        async16(gxl + (long)t*8192 + swo, &sxl[bufi][chunk*512]);
      }
      {  // xt tile: rows of 64B (4 granules), swizzle by row&3 ONLY
        int row = off >> 6;
        int col = off & 63;
        int src = row*4096 + (col ^ ((row & 3) << 4));
        async16(gxtb + (long)t*64 + src, &sxt[bufi][chunk*512]);
      }
    }
  };

  stage(0, 0);
  __syncthreads();

  for (int t = 0; t < ntiles; t++){
    const int cur = t & 1;
    if (t + 1 < ntiles) stage(cur ^ 1, t + 1);
    const char* pxh = (const char*)&sxh[cur][0];
    const char* pxl = (const char*)&sxl[cur][0];

    // ---- S^T tile [32kv x 32q], 3-term hi/lo split ----
    f32x4 sacc[2][2];                          // [kv-half ch][q-half qh]
    sacc[0][0] = f4zero(); sacc[0][1] = f4zero();
    sacc[1][0] = f4zero(); sacc[1][1] = f4zero();
    __builtin_amdgcn_s_setprio(1);
#pragma unroll
    for (int ch = 0; ch < 2; ch++){
      const int rowb = ch*16 + lr;
#pragma unroll
      for (int kc = 0; kc < 4; kc++){
        const int boff = rowb*256 + ((kc*64 + g*16) ^ ((rowb & 7) << 4));
        s16x8 fh = *(const s16x8*)(pxh + boff);
        s16x8 fl = *(const s16x8*)(pxl + boff);
#pragma unroll
        for (int qh = 0; qh < 2; qh++){
          sacc[ch][qh] = MFMA16(fh, byh[qh][kc], sacc[ch][qh]);
          sacc[ch][qh] = MFMA16(fl, byh[qh][kc], sacc[ch][qh]);
          sacc[ch][qh] = MFMA16(fh, byl[qh][kc], sacc[ch][qh]);
        }
      }
    }
    __builtin_amdgcn_s_setprio(0);

    // ---- lane-local online softmax + in-register P^T redistribution ----
    s16x8 bpq[2];
#pragma unroll
    for (int qh = 0; qh < 2; qh++){
      float cm = fmaxf(fmaxf(fmaxf(sacc[0][qh][0], sacc[0][qh][1]),
                             fmaxf(sacc[0][qh][2], sacc[0][qh][3])),
                       fmaxf(fmaxf(sacc[1][qh][0], sacc[1][qh][1]),
                             fmaxf(sacc[1][qh][2], sacc[1][qh][3])));
      cm = fmaxf(cm, __shfl_xor(cm, 16, 64));
      cm = fmaxf(cm, __shfl_xor(cm, 32, 64));
      if (__any(cm > mrun[qh] + 8.f)){         // defer-max (log2 units, P<=256)
        float mn = fmaxf(mrun[qh], cm);
        float sc = exp2f(mrun[qh] - mn);
#pragma unroll
        for (int dg = 0; dg < 8; dg++)
#pragma unroll
          for (int r = 0; r < 4; r++) o[dg][qh][r] *= sc;
        lrun[qh] *= sc;
        mrun[qh] = mn;
      }
      float p[2][4];
#pragma unroll
      for (int ch = 0; ch < 2; ch++)
#pragma unroll
        for (int r = 0; r < 4; r++) p[ch][r] = exp2f(sacc[ch][qh][r] - mrun[qh]);
      float ls = ((p[0][0] + p[0][1]) + (p[0][2] + p[0][3]))
               + ((p[1][0] + p[1][1]) + (p[1][2] + p[1][3]));
      ls += __shfl_xor(ls, 16, 64);
      ls += __shfl_xor(ls, 32, 64);
      lrun[qh] += ls;
      // lane (g,lr) holds P[q=lr+16qh][kv=16ch+4g+r]; B-frag needs kv=8g+j.
      // 4-lane-group permute: sA = 32*(g&1)+lr gives j0..3, sB=sA+16 j4..7, ch=g>>1
      u32 pw00 = pack2bf(p[0][0], p[0][1]);
      u32 pw01 = pack2bf(p[0][2], p[0][3]);
      u32 pw10 = pack2bf(p[1][0], p[1][1]);
      u32 pw11 = pack2bf(p[1][2], p[1][3]);
      int sA = ((g & 1) << 5) + lr;
      int sB = sA + 16;
      u32 a0 = (u32)__shfl((int)pw00, sA, 64);
      u32 a1 = (u32)__shfl((int)pw01, sA, 64);
      u32 a2 = (u32)__shfl((int)pw10, sA, 64);
      u32 a3 = (u32)__shfl((int)pw11, sA, 64);
      u32 b0 = (u32)__shfl((int)pw00, sB, 64);
      u32 b1 = (u32)__shfl((int)pw01, sB, 64);
      u32 b2 = (u32)__shfl((int)pw10, sB, 64);
      u32 b3 = (u32)__shfl((int)pw11, sB, 64);
      bool hi = (g >= 2);
      bpq[qh] = mk8(hi ? a2 : a0, hi ? a3 : a1, hi ? b2 : b0, hi ? b3 : b1);
    }

    // ---- O^T += Xt-frag (LDS swz) x P^T (regs), 2 halves to cap liveness ----
    __builtin_amdgcn_s_setprio(1);
#pragma unroll
    for (int half = 0; half < 2; half++){
      s16x8 ax[4];
#pragma unroll
      for (int i = 0; i < 4; i++){
        int row = (half*4 + i)*16 + lr;
        int phys = row*64 + ((g*16) ^ ((row & 3) << 4));
        ax[i] = *(const s16x8*)((const char*)&sxt[cur][0] + phys);
      }
#pragma unroll
      for (int i = 0; i < 4; i++){
        int dg = half*4 + i;
        o[dg][0] = MFMA16(ax[i], bpq[0], o[dg][0]);
        o[dg][1] = MFMA16(ax[i], bpq[1], o[dg][1]);
      }
    }
    __builtin_amdgcn_s_setprio(0);
    __syncthreads();   // drains prefetch + guards buffer reuse
  }

  // ---- epilogue: O^T lane holds (d = dg*16+4g+r, q = qh*16+lr) ----
  if (KS == 1){
#pragma unroll
    for (int qh = 0; qh < 2; qh++){
      float inv = 1.f / lrun[qh];
      long q = qrow + qh*16 + lr;
#pragma unroll
      for (int dg = 0; dg < 8; dg++){
        u32x2 pw;
        pw[0] = pack2bf(o[dg][qh][0]*inv, o[dg][qh][1]*inv);
        pw[1] = pack2bf(o[dg][qh][2]*inv, o[dg][qh][3]*inv);
        *(u32x2*)(A1bf + q*128 + dg*16 + 4*g) = pw;
      }
    }
  } else {
    const long pid = bid;
#pragma unroll
    for (int qh = 0; qh < 2; qh++){
      int lq = w*32 + qh*16 + lr;
#pragma unroll
      for (int dg = 0; dg < 8; dg++)
        *(f32x4*)(Opart + pid*16384 + (long)lq*128 + dg*16 + 4*g) = o[dg][qh];
      if (g == 0){
        mpart[pid*128 + lq] = mrun[qh];
        lpart[pid*128 + lq] = lrun[qh];
      }
    }
  }
}

// ---------------------------------------------------------------------------
// K4: merge kv-split partials -> normalized A1 (bf16). m's are log2-units.
// ---------------------------------------------------------------------------
__global__ __launch_bounds__(256) void k_merge(
    const float* __restrict__ Opart, const float* __restrict__ mpart, const float* __restrict__ lpart,
    u16* __restrict__ A1bf, int KS)
{
  const int tid = threadIdx.x, bid = blockIdx.x;
  const long R = (long)bid*2 + (tid >> 7);
  const int d = tid & 127;
  const int qb = (int)(R >> 7), r = (int)(R & 127);
  const int pbase = (qb >> 4);                 // batch bits (bid & 7)
  const int qblk  = (qb & 15);
  float m = -1e30f;
  for (int s = 0; s < KS; s++){
    long pid = (long)((qblk*KS + s)*8 + pbase);
    m = fmaxf(m, mpart[pid*128 + r]);
  }
  float acc = 0.f, ls = 0.f;
  for (int s = 0; s < KS; s++){
    long pid = (long)((qblk*KS + s)*8 + pbase);
    float wgt = exp2f(mpart[pid*128 + r] - m);
    ls  += lpart[pid*128 + r] * wgt;
    acc += Opart[pid*16384 + (long)r*128 + d] * wgt;
  }
  A1bf[R*128 + d] = f2bf(acc / ls);
}

// ---------------------------------------------------------------------------
// K5: x1 = relu(A1 @ w1 + x)  (bf16 MFMA, fp32 out)
// ---------------------------------------------------------------------------
__global__ __launch_bounds__(128, 2) void k_layer1(
    const u16* __restrict__ A1bf, const u16* __restrict__ w1t,
    const float* __restrict__ x, float* __restrict__ x1)
{
  __shared__ u16 sb[16384];
  const int tid = threadIdx.x, bid = blockIdx.x;
#pragma unroll
  for (int k = 0; k < 16; k++){
    int off = (tid + k*128)*16;
    int row = off >> 8;
    *(s16x8*)((char*)sb + (off ^ ((row & 7) << 4))) = *(const s16x8*)((const char*)w1t + off);
  }
  __syncthreads();
  const int w = tid >> 6, lane = tid & 63, lr = lane & 15, g = lane >> 4;
  const long rowbase = (long)bid*64 + w*32;
  s16x8 aa[2][4];
#pragma unroll
  for (int rh = 0; rh < 2; rh++)
#pragma unroll
    for (int kc = 0; kc < 4; kc++)
      aa[rh][kc] = *(const s16x8*)(A1bf + (rowbase + rh*16 + lr)*128 + kc*32 + g*8);
  f32x4 acc[2][8];
#pragma unroll
  for (int rh = 0; rh < 2; rh++)
#pragma unroll
    for (int cg = 0; cg < 8; cg++) acc[rh][cg] = f4zero();
  const int swz = (lr & 7) << 4;
#pragma unroll
  for (int cg = 0; cg < 8; cg++){
    const int rowt = (cg*16 + lr)*256;
#pragma unroll
    for (int kc = 0; kc < 4; kc++){
      s16x8 bb = *(const s16x8*)((const char*)sb + rowt + ((kc*64 + g*16) ^ swz));
#pragma unroll
      for (int rh = 0; rh < 2; rh++)
        acc[rh][cg] = MFMA16(aa[rh][kc], bb, acc[rh][cg]);
    }
  }
#pragma unroll
  for (int rh = 0; rh < 2; rh++)
#pragma unroll
    for (int cg = 0; cg < 8; cg++)
#pragma unroll
      for (int r = 0; r < 4; r++){
        long q = rowbase + rh*16 + 4*g + r;
        int  c = cg*16 + lr;
        float v = acc[rh][cg][r] + x[q*128 + c];
        x1[q*128 + c] = fmaxf(v, 0.f);
      }
}

// ---------------------------------------------------------------------------
// K6: exact fp32 row-0 logits  S0[b,m] = (x[b,0,:] @ wr) . x[b,m,:]
// ---------------------------------------------------------------------------
__global__ __launch_bounds__(256) void k_s0(
    const float* __restrict__ x, const float* __restrict__ wr,
    float* __restrict__ S0, float* __restrict__ maxpart)
{
  __shared__ float x0s[128];
  __shared__ float ys[128];
  __shared__ float red[256];
  const int tid = threadIdx.x, bid = blockIdx.x;
  const int b = bid >> 3, j = bid & 7;
  if (tid < 128) x0s[tid] = x[(long)b*262144 + tid];
  __syncthreads();
  if (tid < 128){
    float a = 0.f;
    for (int f = 0; f < 128; f++) a += x0s[f] * wr[f*128 + tid];
    ys[tid] = a;
  }
  __syncthreads();
  const int m = j*256 + tid;
  const float4* xr = (const float4*)(x + ((long)b*2048 + m)*128);
  const float4* yv = (const float4*)ys;
  float acc = 0.f;
#pragma unroll
  for (int f = 0; f < 32; f++){
    float4 a = xr[f], c = yv[f];
    acc += a.x*c.x + a.y*c.y + a.z*c.z + a.w*c.w;
  }
  S0[b*2048 + m] = acc;
  red[tid] = acc;
  __syncthreads();
  for (int sft = 128; sft > 0; sft >>= 1){
    if (tid < sft) red[tid] = fmaxf(red[tid], red[tid + sft]);
    __syncthreads();
  }
  if (tid == 0) maxpart[bid] = red[0];
}

// K7: row-0 softmax (fp32 exact)
__global__ __launch_bounds__(256) void k_r0(
    const float* __restrict__ S0, const float* __restrict__ maxpart, float* __restrict__ R0)
{
  __shared__ float red[256];
  const int tid = threadIdx.x, b = blockIdx.x;
  float M = -1e30f;
#pragma unroll
  for (int jj = 0; jj < 8; jj++) M = fmaxf(M, maxpart[b*8 + jj]);
  float sv[8]; float se = 0.f;
#pragma unroll
  for (int k = 0; k < 8; k++){
    sv[k] = __expf(S0[b*2048 + tid + k*256] - M);
    se += sv[k];
  }
  red[tid] = se;
  __syncthreads();
  for (int sft = 128; sft > 0; sft >>= 1){
    if (tid < sft) red[tid] += red[tid + sft];
    __syncthreads();
  }
  float inv = 1.f / red[0];
#pragma unroll
  for (int k = 0; k < 8; k++) R0[b*2048 + tid + k*256] = sv[k]*inv;
}

// K8: A2 partials  A2p[b,j,:] = sum_{m in chunk j} R0[b,m] * x1[b,m,:]
__global__ __launch_bounds__(256) void k_a2(
    const float* __restrict__ R0, const float* __restrict__ x1, float* __restrict__ A2p)
{
  __shared__ float red[128];
  const int tid = threadIdx.x, bid = blockIdx.x;
  const int b = bid >> 3, j = bid & 7;
  const int d = tid & 127, h = tid >> 7;
  float acc = 0.f;
  for (int mi = j*256 + h; mi < j*256 + 256; mi += 2)
    acc += R0[b*2048 + mi] * x1[((long)b*2048 + mi)*128 + d];
  if (h == 1) red[d] = acc;
  __syncthreads();
  if (h == 0) A2p[(long)bid*128 + d] = acc + red[d];
}

// K9: out = relu(A2 @ w2 + x1[:,0,:])
__global__ __launch_bounds__(256) void k_out(
    const float* __restrict__ A2p, const float* __restrict__ w2,
    const float* __restrict__ x1, float* __restrict__ out)
{
  __shared__ float a2s[2][128];
  const int tid = threadIdx.x, bid = blockIdx.x;
  const int b0 = bid*2;
  {
    int which = tid >> 7, f = tid & 127;
    float s = 0.f;
#pragma unroll
    for (int jj = 0; jj < 8; jj++) s += A2p[(long)((b0 + which)*8 + jj)*128 + f];
    a2s[which][f] = s;
  }
  __syncthreads();
  const int which = tid >> 7, d = tid & 127;
  const int b = b0 + which;
  float acc = x1[(long)b*262144 + d];
  for (int f = 0; f < 128; f++)
    acc += a2s[which][f] * w2[f*128 + d];
  out[b*128 + d] = fmaxf(acc, 0.f);
}

// ---------------------------------------------------------------------------
extern "C" void kernel_launch(void* const* d_in, const int* in_sizes, int n_in,
                              void* d_out, int out_size, void* d_ws, size_t ws_size,
                              hipStream_t stream)
{
  const float* x  = (const float*)d_in[0];
  const float* w1 = (const float*)d_in[1];
  const float* w2 = (const float*)d_in[2];
  const float* wr = (const float*)d_in[3];
  float* out = (float*)d_out;
  char* ws = (char*)d_ws;

  u16*   xh      = (u16*)  (ws + 0);
  u16*   xl      = (u16*)  (ws + 4194304);
  u16*   Xt      = (u16*)  (ws + 8388608);
  u16*   yh      = (u16*)  (ws + 12582912);
  u16*   yl      = (u16*)  (ws + 16777216);
  u16*   wrth    = (u16*)  (ws + 20971520);
  u16*   wrtl    = (u16*)  (ws + 21004288);
  u16*   w1t     = (u16*)  (ws + 21037056);
  u16*   A1bf    = (u16*)  (ws + 21069824);
  float* R0      = (float*)(ws + 25264128);
  float* S0      = (float*)(ws + 25329664);
  float* maxpart = (float*)(ws + 25395200);
  float* A2p     = (float*)(ws + 25396224);
  // flash partials live in [tail, ...) and are DEAD before x1 is written,
  // so x1 aliases the same region (written by k_layer1 after k_merge).
  const size_t tail = 25428992;

  int KS = 4, kslog = 2;
  // per-KS bytes: mpart 64K + lpart 64K + Opart (128*16384*4)=8M  => 8519680
  while (KS > 1 && tail + (size_t)KS*8519680ull > ws_size){ KS >>= 1; kslog--; }
  float* mpart = (float*)(ws + tail);
  float* lpart = (float*)(ws + tail + (size_t)KS*65536);
  float* Opart = (float*)(ws + tail + (size_t)KS*131072);
  float* x1    = (float*)(ws + tail);          // aliases mpart/lpart/Opart (dead)

  k_prep  <<<1024, 256, 0, stream>>>(x, wr, w1, xh, xl, Xt, wrth, wrtl, w1t);
  k_ygemm <<<256, 128, 0, stream>>>(xh, xl, wrth, wrtl, yh, yl);
  k_flash <<<128*KS, 256, 0, stream>>>(xh, xl, Xt, yh, yl, A1bf, Opart, mpart, lpart, KS, kslog);
  if (KS > 1)
    k_merge <<<8192, 256, 0, stream>>>(Opart, mpart, lpart, A1bf, KS);
  k_layer1<<<256, 128, 0, stream>>>(A1bf, w1t, x, x1);
  k_s0    <<<64, 256, 0, stream>>>(x, wr, S0, maxpart);
  k_r0    <<<8, 256, 0, stream>>>(S0, maxpart, R0);
  k_a2    <<<64, 256, 0, stream>>>(R0, x1, A2p);
  k_out   <<<4, 256, 0, stream>>>(A2p, w2, x1, out);
}

// Round 5
// 147.878 us; speedup vs baseline: 1.5230x; 1.2153x over previous
//
#include <hip/hip_runtime.h>
#include <stdint.h>

typedef float  f32x4 __attribute__((ext_vector_type(4)));
typedef short  s16x8 __attribute__((ext_vector_type(8)));
typedef unsigned int u32;
typedef u32    u32x2 __attribute__((ext_vector_type(2)));
typedef u32    u32x4 __attribute__((ext_vector_type(4)));
typedef unsigned short u16;

#define MFMA16(a,b,c) __builtin_amdgcn_mfma_f32_16x16x32_bf16((a),(b),(c),0,0,0)

__device__ __forceinline__ u16 f2bf(float f){
  u32 u = __float_as_uint(f);
  return (u16)((u + 0x7fffu + ((u >> 16) & 1u)) >> 16);   // RNE
}
__device__ __forceinline__ float bf2f(u16 h){ return __uint_as_float(((u32)h) << 16); }
__device__ __forceinline__ u32 pack2bf(float a, float b){ return (u32)f2bf(a) | ((u32)f2bf(b) << 16); }
__device__ __forceinline__ f32x4 f4zero(){ f32x4 z; z[0]=0.f; z[1]=0.f; z[2]=0.f; z[3]=0.f; return z; }
// register-only vector build (NO union: unions can defeat SROA -> scratch)
__device__ __forceinline__ s16x8 mk8(u32 a, u32 b, u32 c, u32 d){
  u32x4 w; w[0]=a; w[1]=b; w[2]=c; w[3]=d;
  return __builtin_bit_cast(s16x8, w);
}

// async global->LDS, 16B per lane; LDS dest is wave-uniform base + lane*16
__device__ __forceinline__ void async16(const void* g, void* l){
  __builtin_amdgcn_global_load_lds(
      (const __attribute__((address_space(1))) unsigned int*)g,
      (__attribute__((address_space(3))) unsigned int*)l, 16, 0, 0);
}

// ---------------------------------------------------------------------------
// K1: split x -> xh/xl (bf16 hi/lo), build Xt (bf16 x transposed per batch),
//     and (block 0/1) prep wr^T hi/lo and w1^T bf16.
// ---------------------------------------------------------------------------
__global__ __launch_bounds__(256) void k_prep(
    const float* __restrict__ x, const float* __restrict__ wr, const float* __restrict__ w1,
    u16* __restrict__ xh, u16* __restrict__ xl, u16* __restrict__ Xt,
    u16* __restrict__ wrth, u16* __restrict__ wrtl, u16* __restrict__ w1t)
{
  __shared__ float xs[16][132];
  const int tid = threadIdx.x, bid = blockIdx.x;
  const long base = (long)bid * 2048;          // 16 rows * 128
#pragma unroll
  for (int k = 0; k < 8; k++){
    int idx = tid + k*256;
    float v = x[base + idx];
    xs[idx>>7][idx&127] = v;
    u16 h = f2bf(v);
    xh[base+idx] = h;
    xl[base+idx] = f2bf(v - bf2f(h));
  }
  __syncthreads();
  const int b  = bid >> 7;                     // 128 blocks per batch
  const int n0 = (bid & 127) * 16;
  const int nn = tid & 15, d0 = tid >> 4;
#pragma unroll
  for (int d = 0; d < 8; d++){
    int dd = d0 + d*16;
    Xt[(long)b*262144 + (long)dd*2048 + n0 + nn] = f2bf(xs[nn][dd]);
  }
  if (bid == 0){
#pragma unroll
    for (int k = 0; k < 64; k++){
      int idx = tid + k*256;
      int g = idx >> 7, f = idx & 127;
      float v = wr[f*128 + g];                 // wrT[g][f] = wr[f][g]
      u16 h = f2bf(v);
      wrth[idx] = h;
      wrtl[idx] = f2bf(v - bf2f(h));
    }
  } else if (bid == 1){
#pragma unroll
    for (int k = 0; k < 64; k++){
      int idx = tid + k*256;
      int c = idx >> 7, f = idx & 127;
      w1t[idx] = f2bf(w1[f*128 + c]);          // w1T[c][f] = w1[f][c]
    }
  }
}

// ---------------------------------------------------------------------------
// K2: y = (x @ wr) * log2(e)  via 3-term split bf16 MFMA; write yh/yl hi/lo
// ---------------------------------------------------------------------------
__global__ __launch_bounds__(128, 2) void k_ygemm(
    const u16* __restrict__ xh, const u16* __restrict__ xl,
    const u16* __restrict__ wrth, const u16* __restrict__ wrtl,
    u16* __restrict__ yh, u16* __restrict__ yl)
{
  __shared__ u16 sbh[16384], sbl[16384];       // [c][f] bf16, XOR-swizzled
  const int tid = threadIdx.x, bid = blockIdx.x;
#pragma unroll
  for (int k = 0; k < 16; k++){
    int off = (tid + k*128) * 16;
    int row = off >> 8;
    int dst = off ^ ((row & 7) << 4);
    *(s16x8*)((char*)sbh + dst) = *(const s16x8*)((const char*)wrth + off);
    *(s16x8*)((char*)sbl + dst) = *(const s16x8*)((const char*)wrtl + off);
  }
  __syncthreads();
  const int w = tid >> 6, lane = tid & 63, lr = lane & 15, g = lane >> 4;
  const long rowbase = (long)bid*64 + w*32;
  s16x8 ah[2][4], al[2][4];
#pragma unroll
  for (int rh = 0; rh < 2; rh++)
#pragma unroll
    for (int kc = 0; kc < 4; kc++){
      long r = rowbase + rh*16 + lr;
      ah[rh][kc] = *(const s16x8*)(xh + r*128 + kc*32 + g*8);
      al[rh][kc] = *(const s16x8*)(xl + r*128 + kc*32 + g*8);
    }
  f32x4 acc[2][8];
#pragma unroll
  for (int rh = 0; rh < 2; rh++)
#pragma unroll
    for (int cg = 0; cg < 8; cg++) acc[rh][cg] = f4zero();
  const int swz = (lr & 7) << 4;
#pragma unroll
  for (int cg = 0; cg < 8; cg++){
    const int rowt = (cg*16 + lr) * 256;
#pragma unroll
    for (int kc = 0; kc < 4; kc++){
      int boff = rowt + ((kc*64 + g*16) ^ swz);
      s16x8 bh = *(const s16x8*)((const char*)sbh + boff);
      s16x8 bl = *(const s16x8*)((const char*)sbl + boff);
#pragma unroll
      for (int rh = 0; rh < 2; rh++){
        acc[rh][cg] = MFMA16(ah[rh][kc], bh, acc[rh][cg]);
        acc[rh][cg] = MFMA16(al[rh][kc], bh, acc[rh][cg]);
        acc[rh][cg] = MFMA16(ah[rh][kc], bl, acc[rh][cg]);
      }
    }
  }
#pragma unroll
  for (int rh = 0; rh < 2; rh++)
#pragma unroll
    for (int cg = 0; cg < 8; cg++)
#pragma unroll
      for (int r = 0; r < 4; r++){
        long q = rowbase + rh*16 + 4*g + r;    // C-layout: row=(l>>4)*4+reg
        int  c = cg*16 + lr;                   //           col=l&15
        float v = acc[rh][cg][r] * 1.4426950408889634f;
        u16 h = f2bf(v);
        yh[q*128 + c] = h;
        yl[q*128 + c] = f2bf(v - bf2f(h));
      }
}

// ---------------------------------------------------------------------------
// K3: fused flash, swapped-operand form, all tiles LDS-staged + swizzled.
//   S^T tile = X_tile (LDS, A-op) x Y^T (regs, B-op)  -> lane-local softmax
//   P redistributed in-register via 8 shfl + selects (no LDS bounce)
//   O^T     += Xt_tile (LDS, A-op) x P^T (regs, B-op)
//   sxt rows are 64B = 4x16B granules -> swizzle mask (row&3)<<4 (bijective).
//   launch_bounds (256,2): (256,3) caused VGPR squeeze -> scratch spills ->
//   ~120MB phantom HBM writes (rounds 2&4 signature: VGPR_Count 84).
//   grid = 8 batches (XCD-pinned) * 16 qbl * KS
// ---------------------------------------------------------------------------
__global__ __launch_bounds__(256, 2) void k_flash(
    const u16* __restrict__ xh, const u16* __restrict__ xl, const u16* __restrict__ Xt,
    const u16* __restrict__ yh, const u16* __restrict__ yl,
    u16* __restrict__ A1bf,
    float* __restrict__ Opart, float* __restrict__ mpart, float* __restrict__ lpart,
    int KS, int kslog)
{
  __shared__ u16 sxh[2][4096], sxl[2][4096];   // 32kv x 128f, XOR-swz (row&7)
  __shared__ u16 sxt[2][4096];                 // 128d x 32kv, XOR-swz (row&3)
  const int tid = threadIdx.x, bid = blockIdx.x;
  const int b     = bid & 7;                   // XCD b owns batch b
  const int inner = bid >> 3;
  const int s     = inner & (KS - 1);
  const int qbl   = inner >> kslog;
  const int qb    = b*16 + qbl;
  const int nspan = 2048 >> kslog;
  const int kv0   = s * nspan;
  const int ntiles = nspan >> 5;
  const int w = tid >> 6, lane = tid & 63, lr = lane & 15, g = lane >> 4;
  const long qrow = (long)qb*128 + w*32;

  // Y fragments (B-operands), hi/lo — per-warp constants
  s16x8 byh[2][4], byl[2][4];
#pragma unroll
  for (int qh = 0; qh < 2; qh++)
#pragma unroll
    for (int kc = 0; kc < 4; kc++){
      long r = qrow + qh*16 + lr;
      byh[qh][kc] = *(const s16x8*)(yh + r*128 + kc*32 + g*8);
      byl[qh][kc] = *(const s16x8*)(yl + r*128 + kc*32 + g*8);
    }

  f32x4 o[8][2];                               // O^T: [d-tile dg][q-half qh]
#pragma unroll
  for (int dg = 0; dg < 8; dg++){ o[dg][0] = f4zero(); o[dg][1] = f4zero(); }
  float mrun[2] = {-1e30f, -1e30f}, lrun[2] = {0.f, 0.f};

  const char* gxh  = (const char*)xh + ((long)b*2048 + kv0)*256;
  const char* gxl  = (const char*)xl + ((long)b*2048 + kv0)*256;
  const char* gxtb = (const char*)(Xt + (long)b*262144 + kv0);

  auto stage = [&](int bufi, int t){
#pragma unroll
    for (int c2 = 0; c2 < 2; c2++){
      int chunk = w*2 + c2;
      int off = chunk*1024 + lane*16;
      {  // x tiles: rows of 256B (16 granules), swizzle by row&7
        int row = off >> 8;
        int swo = off ^ ((row & 7) << 4);
        async16(gxh + (long)t*8192 + swo, &sxh[bufi][chunk*512]);
        async16(gxl + (long)t*8192 + swo, &sxl[bufi][chunk*512]);
      }
      {  // xt tile: rows of 64B (4 granules), swizzle by row&3 ONLY
        int row = off >> 6;
        int col = off & 63;
        int src = row*4096 + (col ^ ((row & 3) << 4));
        async16(gxtb + (long)t*64 + src, &sxt[bufi][chunk*512]);
      }
    }
  };

  stage(0, 0);
  __syncthreads();

  for (int t = 0; t < ntiles; t++){
    const int cur = t & 1;
    if (t + 1 < ntiles) stage(cur ^ 1, t + 1);
    const char* pxh = (const char*)&sxh[cur][0];
    const char* pxl = (const char*)&sxl[cur][0];

    // ---- S^T tile [32kv x 32q], 3-term hi/lo split ----
    f32x4 sacc[2][2];                          // [kv-half ch][q-half qh]
    sacc[0][0] = f4zero(); sacc[0][1] = f4zero();
    sacc[1][0] = f4zero(); sacc[1][1] = f4zero();
    __builtin_amdgcn_s_setprio(1);
#pragma unroll
    for (int ch = 0; ch < 2; ch++){
      const int rowb = ch*16 + lr;
#pragma unroll
      for (int kc = 0; kc < 4; kc++){
        const int boff = rowb*256 + ((kc*64 + g*16) ^ ((rowb & 7) << 4));
        s16x8 fh = *(const s16x8*)(pxh + boff);
        s16x8 fl = *(const s16x8*)(pxl + boff);
#pragma unroll
        for (int qh = 0; qh < 2; qh++){
          sacc[ch][qh] = MFMA16(fh, byh[qh][kc], sacc[ch][qh]);
          sacc[ch][qh] = MFMA16(fl, byh[qh][kc], sacc[ch][qh]);
          sacc[ch][qh] = MFMA16(fh, byl[qh][kc], sacc[ch][qh]);
        }
      }
    }
    __builtin_amdgcn_s_setprio(0);

    // ---- lane-local online softmax + in-register P^T redistribution ----
    s16x8 bpq[2];
#pragma unroll
    for (int qh = 0; qh < 2; qh++){
      float cm = fmaxf(fmaxf(fmaxf(sacc[0][qh][0], sacc[0][qh][1]),
                             fmaxf(sacc[0][qh][2], sacc[0][qh][3])),
                       fmaxf(fmaxf(sacc[1][qh][0], sacc[1][qh][1]),
                             fmaxf(sacc[1][qh][2], sacc[1][qh][3])));
      cm = fmaxf(cm, __shfl_xor(cm, 16, 64));
      cm = fmaxf(cm, __shfl_xor(cm, 32, 64));
      if (__any(cm > mrun[qh] + 8.f)){         // defer-max (log2 units, P<=256)
        float mn = fmaxf(mrun[qh], cm);
        float sc = exp2f(mrun[qh] - mn);
#pragma unroll
        for (int dg = 0; dg < 8; dg++)
#pragma unroll
          for (int r = 0; r < 4; r++) o[dg][qh][r] *= sc;
        lrun[qh] *= sc;
        mrun[qh] = mn;
      }
      float p[2][4];
#pragma unroll
      for (int ch = 0; ch < 2; ch++)
#pragma unroll
        for (int r = 0; r < 4; r++) p[ch][r] = exp2f(sacc[ch][qh][r] - mrun[qh]);
      float ls = ((p[0][0] + p[0][1]) + (p[0][2] + p[0][3]))
               + ((p[1][0] + p[1][1]) + (p[1][2] + p[1][3]));
      ls += __shfl_xor(ls, 16, 64);
      ls += __shfl_xor(ls, 32, 64);
      lrun[qh] += ls;
      // lane (g,lr) holds P[q=lr+16qh][kv=16ch+4g+r]; B-frag needs kv=8g+j.
      // 4-lane-group permute: sA = 32*(g&1)+lr gives j0..3, sB=sA+16 j4..7, ch=g>>1
      u32 pw00 = pack2bf(p[0][0], p[0][1]);
      u32 pw01 = pack2bf(p[0][2], p[0][3]);
      u32 pw10 = pack2bf(p[1][0], p[1][1]);
      u32 pw11 = pack2bf(p[1][2], p[1][3]);
      int sA = ((g & 1) << 5) + lr;
      int sB = sA + 16;
      u32 a0 = (u32)__shfl((int)pw00, sA, 64);
      u32 a1 = (u32)__shfl((int)pw01, sA, 64);
      u32 a2 = (u32)__shfl((int)pw10, sA, 64);
      u32 a3 = (u32)__shfl((int)pw11, sA, 64);
      u32 b0 = (u32)__shfl((int)pw00, sB, 64);
      u32 b1 = (u32)__shfl((int)pw01, sB, 64);
      u32 b2 = (u32)__shfl((int)pw10, sB, 64);
      u32 b3 = (u32)__shfl((int)pw11, sB, 64);
      bool hi = (g >= 2);
      bpq[qh] = mk8(hi ? a2 : a0, hi ? a3 : a1, hi ? b2 : b0, hi ? b3 : b1);
    }

    // ---- O^T += Xt-frag (LDS swz) x P^T (regs), 2 halves to cap liveness ----
    __builtin_amdgcn_s_setprio(1);
#pragma unroll
    for (int half = 0; half < 2; half++){
      s16x8 ax[4];
#pragma unroll
      for (int i = 0; i < 4; i++){
        int row = (half*4 + i)*16 + lr;
        int phys = row*64 + ((g*16) ^ ((row & 3) << 4));
        ax[i] = *(const s16x8*)((const char*)&sxt[cur][0] + phys);
      }
#pragma unroll
      for (int i = 0; i < 4; i++){
        int dg = half*4 + i;
        o[dg][0] = MFMA16(ax[i], bpq[0], o[dg][0]);
        o[dg][1] = MFMA16(ax[i], bpq[1], o[dg][1]);
      }
    }
    __builtin_amdgcn_s_setprio(0);
    __syncthreads();   // drains prefetch + guards buffer reuse
  }

  // ---- epilogue: O^T lane holds (d = dg*16+4g+r, q = qh*16+lr) ----
  if (KS == 1){
#pragma unroll
    for (int qh = 0; qh < 2; qh++){
      float inv = 1.f / lrun[qh];
      long q = qrow + qh*16 + lr;
#pragma unroll
      for (int dg = 0; dg < 8; dg++){
        u32x2 pw;
        pw[0] = pack2bf(o[dg][qh][0]*inv, o[dg][qh][1]*inv);
        pw[1] = pack2bf(o[dg][qh][2]*inv, o[dg][qh][3]*inv);
        *(u32x2*)(A1bf + q*128 + dg*16 + 4*g) = pw;
      }
    }
  } else {
    const long pid = bid;
#pragma unroll
    for (int qh = 0; qh < 2; qh++){
      int lq = w*32 + qh*16 + lr;
#pragma unroll
      for (int dg = 0; dg < 8; dg++)
        *(f32x4*)(Opart + pid*16384 + (long)lq*128 + dg*16 + 4*g) = o[dg][qh];
      if (g == 0){
        mpart[pid*128 + lq] = mrun[qh];
        lpart[pid*128 + lq] = lrun[qh];
      }
    }
  }
}

// ---------------------------------------------------------------------------
// K4: merge kv-split partials -> normalized A1 (bf16). m's are log2-units.
// ---------------------------------------------------------------------------
__global__ __launch_bounds__(256) void k_merge(
    const float* __restrict__ Opart, const float* __restrict__ mpart, const float* __restrict__ lpart,
    u16* __restrict__ A1bf, int KS)
{
  const int tid = threadIdx.x, bid = blockIdx.x;
  const long R = (long)bid*2 + (tid >> 7);
  const int d = tid & 127;
  const int qb = (int)(R >> 7), r = (int)(R & 127);
  const int pbase = (qb >> 4);                 // batch bits (bid & 7)
  const int qblk  = (qb & 15);
  float m = -1e30f;
  for (int s = 0; s < KS; s++){
    long pid = (long)((qblk*KS + s)*8 + pbase);
    m = fmaxf(m, mpart[pid*128 + r]);
  }
  float acc = 0.f, ls = 0.f;
  for (int s = 0; s < KS; s++){
    long pid = (long)((qblk*KS + s)*8 + pbase);
    float wgt = exp2f(mpart[pid*128 + r] - m);
    ls  += lpart[pid*128 + r] * wgt;
    acc += Opart[pid*16384 + (long)r*128 + d] * wgt;
  }
  A1bf[R*128 + d] = f2bf(acc / ls);
}

// ---------------------------------------------------------------------------
// K5: x1 = relu(A1 @ w1 + x)  (bf16 MFMA, fp32 out)
// ---------------------------------------------------------------------------
__global__ __launch_bounds__(128, 2) void k_layer1(
    const u16* __restrict__ A1bf, const u16* __restrict__ w1t,
    const float* __restrict__ x, float* __restrict__ x1)
{
  __shared__ u16 sb[16384];
  const int tid = threadIdx.x, bid = blockIdx.x;
#pragma unroll
  for (int k = 0; k < 16; k++){
    int off = (tid + k*128)*16;
    int row = off >> 8;
    *(s16x8*)((char*)sb + (off ^ ((row & 7) << 4))) = *(const s16x8*)((const char*)w1t + off);
  }
  __syncthreads();
  const int w = tid >> 6, lane = tid & 63, lr = lane & 15, g = lane >> 4;
  const long rowbase = (long)bid*64 + w*32;
  s16x8 aa[2][4];
#pragma unroll
  for (int rh = 0; rh < 2; rh++)
#pragma unroll
    for (int kc = 0; kc < 4; kc++)
      aa[rh][kc] = *(const s16x8*)(A1bf + (rowbase + rh*16 + lr)*128 + kc*32 + g*8);
  f32x4 acc[2][8];
#pragma unroll
  for (int rh = 0; rh < 2; rh++)
#pragma unroll
    for (int cg = 0; cg < 8; cg++) acc[rh][cg] = f4zero();
  const int swz = (lr & 7) << 4;
#pragma unroll
  for (int cg = 0; cg < 8; cg++){
    const int rowt = (cg*16 + lr)*256;
#pragma unroll
    for (int kc = 0; kc < 4; kc++){
      s16x8 bb = *(const s16x8*)((const char*)sb + rowt + ((kc*64 + g*16) ^ swz));
#pragma unroll
      for (int rh = 0; rh < 2; rh++)
        acc[rh][cg] = MFMA16(aa[rh][kc], bb, acc[rh][cg]);
    }
  }
#pragma unroll
  for (int rh = 0; rh < 2; rh++)
#pragma unroll
    for (int cg = 0; cg < 8; cg++)
#pragma unroll
      for (int r = 0; r < 4; r++){
        long q = rowbase + rh*16 + 4*g + r;
        int  c = cg*16 + lr;
        float v = acc[rh][cg][r] + x[q*128 + c];
        x1[q*128 + c] = fmaxf(v, 0.f);
      }
}

// ---------------------------------------------------------------------------
// K6: exact fp32 row-0 logits  S0[b,m] = (x[b,0,:] @ wr) . x[b,m,:]
// ---------------------------------------------------------------------------
__global__ __launch_bounds__(256) void k_s0(
    const float* __restrict__ x, const float* __restrict__ wr,
    float* __restrict__ S0, float* __restrict__ maxpart)
{
  __shared__ float x0s[128];
  __shared__ float ys[128];
  __shared__ float red[256];
  const int tid = threadIdx.x, bid = blockIdx.x;
  const int b = bid >> 3, j = bid & 7;
  if (tid < 128) x0s[tid] = x[(long)b*262144 + tid];
  __syncthreads();
  if (tid < 128){
    float a = 0.f;
    for (int f = 0; f < 128; f++) a += x0s[f] * wr[f*128 + tid];
    ys[tid] = a;
  }
  __syncthreads();
  const int m = j*256 + tid;
  const float4* xr = (const float4*)(x + ((long)b*2048 + m)*128);
  const float4* yv = (const float4*)ys;
  float acc = 0.f;
#pragma unroll
  for (int f = 0; f < 32; f++){
    float4 a = xr[f], c = yv[f];
    acc += a.x*c.x + a.y*c.y + a.z*c.z + a.w*c.w;
  }
  S0[b*2048 + m] = acc;
  red[tid] = acc;
  __syncthreads();
  for (int sft = 128; sft > 0; sft >>= 1){
    if (tid < sft) red[tid] = fmaxf(red[tid], red[tid + sft]);
    __syncthreads();
  }
  if (tid == 0) maxpart[bid] = red[0];
}

// K7: row-0 softmax (fp32 exact)
__global__ __launch_bounds__(256) void k_r0(
    const float* __restrict__ S0, const float* __restrict__ maxpart, float* __restrict__ R0)
{
  __shared__ float red[256];
  const int tid = threadIdx.x, b = blockIdx.x;
  float M = -1e30f;
#pragma unroll
  for (int jj = 0; jj < 8; jj++) M = fmaxf(M, maxpart[b*8 + jj]);
  float sv[8]; float se = 0.f;
#pragma unroll
  for (int k = 0; k < 8; k++){
    sv[k] = __expf(S0[b*2048 + tid + k*256] - M);
    se += sv[k];
  }
  red[tid] = se;
  __syncthreads();
  for (int sft = 128; sft > 0; sft >>= 1){
    if (tid < sft) red[tid] += red[tid + sft];
    __syncthreads();
  }
  float inv = 1.f / red[0];
#pragma unroll
  for (int k = 0; k < 8; k++) R0[b*2048 + tid + k*256] = sv[k]*inv;
}

// K8: A2 partials  A2p[b,j,:] = sum_{m in chunk j} R0[b,m] * x1[b,m,:]
__global__ __launch_bounds__(256) void k_a2(
    const float* __restrict__ R0, const float* __restrict__ x1, float* __restrict__ A2p)
{
  __shared__ float red[128];
  const int tid = threadIdx.x, bid = blockIdx.x;
  const int b = bid >> 3, j = bid & 7;
  const int d = tid & 127, h = tid >> 7;
  float acc = 0.f;
  for (int mi = j*256 + h; mi < j*256 + 256; mi += 2)
    acc += R0[b*2048 + mi] * x1[((long)b*2048 + mi)*128 + d];
  if (h == 1) red[d] = acc;
  __syncthreads();
  if (h == 0) A2p[(long)bid*128 + d] = acc + red[d];
}

// K9: out = relu(A2 @ w2 + x1[:,0,:])
__global__ __launch_bounds__(256) void k_out(
    const float* __restrict__ A2p, const float* __restrict__ w2,
    const float* __restrict__ x1, float* __restrict__ out)
{
  __shared__ float a2s[2][128];
  const int tid = threadIdx.x, bid = blockIdx.x;
  const int b0 = bid*2;
  {
    int which = tid >> 7, f = tid & 127;
    float s = 0.f;
#pragma unroll
    for (int jj = 0; jj < 8; jj++) s += A2p[(long)((b0 + which)*8 + jj)*128 + f];
    a2s[which][f] = s;
  }
  __syncthreads();
  const int which = tid >> 7, d = tid & 127;
  const int b = b0 + which;
  float acc = x1[(long)b*262144 + d];
  for (int f = 0; f < 128; f++)
    acc += a2s[which][f] * w2[f*128 + d];
  out[b*128 + d] = fmaxf(acc, 0.f);
}

// ---------------------------------------------------------------------------
extern "C" void kernel_launch(void* const* d_in, const int* in_sizes, int n_in,
                              void* d_out, int out_size, void* d_ws, size_t ws_size,
                              hipStream_t stream)
{
  const float* x  = (const float*)d_in[0];
  const float* w1 = (const float*)d_in[1];
  const float* w2 = (const float*)d_in[2];
  const float* wr = (const float*)d_in[3];
  float* out = (float*)d_out;
  char* ws = (char*)d_ws;

  u16*   xh      = (u16*)  (ws + 0);
  u16*   xl      = (u16*)  (ws + 4194304);
  u16*   Xt      = (u16*)  (ws + 8388608);
  u16*   yh      = (u16*)  (ws + 12582912);
  u16*   yl      = (u16*)  (ws + 16777216);
  u16*   wrth    = (u16*)  (ws + 20971520);
  u16*   wrtl    = (u16*)  (ws + 21004288);
  u16*   w1t     = (u16*)  (ws + 21037056);
  u16*   A1bf    = (u16*)  (ws + 21069824);
  float* R0      = (float*)(ws + 25264128);
  float* S0      = (float*)(ws + 25329664);
  float* maxpart = (float*)(ws + 25395200);
  float* A2p     = (float*)(ws + 25396224);
  // flash partials live in [tail, ...) and are DEAD before x1 is written,
  // so x1 aliases the same region (written by k_layer1 after k_merge).
  const size_t tail = 25428992;

  int KS = 4, kslog = 2;
  // per-KS bytes: mpart 64K + lpart 64K + Opart (128*16384*4)=8M  => 8519680
  while (KS > 1 && tail + (size_t)KS*8519680ull > ws_size){ KS >>= 1; kslog--; }
  float* mpart = (float*)(ws + tail);
  float* lpart = (float*)(ws + tail + (size_t)KS*65536);
  float* Opart = (float*)(ws + tail + (size_t)KS*131072);
  float* x1    = (float*)(ws + tail);          // aliases mpart/lpart/Opart (dead)

  k_prep  <<<1024, 256, 0, stream>>>(x, wr, w1, xh, xl, Xt, wrth, wrtl, w1t);
  k_ygemm <<<256, 128, 0, stream>>>(xh, xl, wrth, wrtl, yh, yl);
  k_flash <<<128*KS, 256, 0, stream>>>(xh, xl, Xt, yh, yl, A1bf, Opart, mpart, lpart, KS, kslog);
  if (KS > 1)
    k_merge <<<8192, 256, 0, stream>>>(Opart, mpart, lpart, A1bf, KS);
  k_layer1<<<256, 128, 0, stream>>>(A1bf, w1t, x, x1);
  k_s0    <<<64, 256, 0, stream>>>(x, wr, S0, maxpart);
  k_r0    <<<8, 256, 0, stream>>>(S0, maxpart, R0);
  k_a2    <<<64, 256, 0, stream>>>(R0, x1, A2p);
  k_out   <<<4, 256, 0, stream>>>(A2p, w2, x1, out);
}